// Round 7
// baseline (8841.096 us; speedup 1.0000x reference)
//
#include <hip/hip_runtime.h>

#define Bsz 4096
#define Lsz 128
#define NI  127
#define SD  32
#define AD  8
#define LAT 64
#define HID 128
#define BT  16
#define THR 1024

typedef float f32x2 __attribute__((ext_vector_type(2)));
typedef float f32x4 __attribute__((ext_vector_type(4)));

// ---------------- W2 repack ----------------
// W2 [128][64][9] -> W2p8 [j][l][8] (channels 1..8, 32B rows) + W2c0 [j][l] (channel 0)
__global__ __launch_bounds__(256) void repack_w2(const float* __restrict__ W2,
                                                 float* __restrict__ W2p8,
                                                 float* __restrict__ W2c0){
  int idx = blockIdx.x*256 + threadIdx.x;
  if (idx < HID*LAT*8){
    int x = idx & 7; int jl = idx >> 3; int l = jl & 63; int j = jl >> 6;
    W2p8[idx] = W2[(j*LAT + l)*9 + x + 1];
  } else if (idx < HID*LAT*9){
    int jl = idx - HID*LAT*8;
    W2c0[jl] = W2[(size_t)jl*9];
  }
}

// ---------------- Natural cubic spline: channels 1..8 (t-channel exactly linear) ----------------
__global__ __launch_bounds__(256) void spline_kernel(const float* __restrict__ a,
                                                     float* __restrict__ m_ws){
  __shared__ float cp_s[126];
  if (threadIdx.x == 0){
    float c = 0.25f; cp_s[0] = c;
    for (int i=1;i<126;i++){ c = 1.0f/(4.0f - c); cp_s[i] = c; }
  }
  __syncthreads();
  int tid = blockIdx.x*256 + threadIdx.x;   // tid = b*8 + c8
  int b = tid >> 3, c8 = tid & 7;
  float dp[126];
  const float* ab = a + (size_t)b*Lsz*AD + c8;
  float x0 = ab[0];
  float x1 = ab[AD];
  for (int i=0;i<126;i++){
    float x2 = ab[(size_t)(i+2)*AD];
    float rhs = 6.0f*(x2 - 2.0f*x1 + x0);
    dp[i] = (i==0)? rhs*0.25f : (rhs - dp[i-1])*cp_s[i];
    x0 = x1; x1 = x2;
  }
  m_ws[tid] = 0.0f;
  m_ws[((size_t)127*Bsz)*8 + tid] = 0.0f;
  float mn = 0.0f;
  for (int k=125;k>=0;k--){
    mn = dp[k] - cp_s[k]*mn;
    m_ws[((size_t)(k+1)*Bsz)*8 + tid] = mn;
  }
}

// ---- cross-lane helpers (32-bit) ----
#define DPP_XOR1(v) __int_as_float(__builtin_amdgcn_mov_dpp(__float_as_int(v), 0xB1, 0xF, 0xF, true))
#define DPP_XOR2(v) __int_as_float(__builtin_amdgcn_mov_dpp(__float_as_int(v), 0x4E, 0xF, 0xF, true))
#define SWZ_XOR4(v) __int_as_float(__builtin_amdgcn_ds_swizzle(__float_as_int(v), 0x101F))
#define SWZ_XOR8(v) __int_as_float(__builtin_amdgcn_ds_swizzle(__float_as_int(v), 0x201F))

// ---- packed fp32 ops (VOP3P). BCLO/BCHI broadcast src0's lo/hi half to both result halves ----
#define PK_MUL_BCLO(d, w, x) asm("v_pk_mul_f32 %0, %1, %2 op_sel:[0,0] op_sel_hi:[0,1]" : "=v"(d) : "v"(w), "v"(x))
#define PK_FMA_BCLO(acc, w, x) asm("v_pk_fma_f32 %0, %1, %2, %0 op_sel:[0,0,0] op_sel_hi:[0,1,1]" : "+v"(acc) : "v"(w), "v"(x))
#define PK_FMA_BCHI(acc, w, x) asm("v_pk_fma_f32 %0, %1, %2, %0 op_sel:[1,0,0] op_sel_hi:[1,1,1]" : "+v"(acc) : "v"(w), "v"(x))
#define PK_FMA(acc, a, b)      asm("v_pk_fma_f32 %0, %1, %2, %0" : "+v"(acc) : "v"(a), "v"(b))
#define PK_ADD(d, a, b)        asm("v_pk_add_f32 %0, %1, %2" : "=v"(d) : "v"(a), "v"(b))

#define LO2(v4) __builtin_shufflevector(v4, v4, 0, 1)
#define HI2(v4) __builtin_shufflevector(v4, v4, 2, 3)

// LDS strides (floats)
#define HPROW 324   // hp: [pair p][jblk=jg][jj][2], jblk stride 20, row = 16*20+4
#define DXROW 20    // dXp: [ui][pair p][x8][2], pair stride 20, ui stride 160

// ---------------- Persistent RK4 integrator: packed-fp32 GEMM2 ----------------
__attribute__((amdgpu_waves_per_eu(4,4)))
__global__ __launch_bounds__(THR) void cde_integrate(
    const float* __restrict__ s, const float* __restrict__ a, const float* __restrict__ t,
    const float* __restrict__ encW, const float* __restrict__ encb,
    const float* __restrict__ W1, const float* __restrict__ b1,
    const float* __restrict__ b2, const float* __restrict__ decW, const float* __restrict__ decb,
    const float* __restrict__ W2p8, const float* __restrict__ W2c0, const float* __restrict__ m_ws,
    float* __restrict__ out)
{
  __shared__ float W1t[HID][LAT+4];     // [j][k]
  __shared__ float hp[8*HPROW];         // h in b-pair layout
  __shared__ float zs[BT][LAT+4];       // [b][l]
  __shared__ float dXp[5*160];          // dX in b-pair layout per u
  __shared__ float dWs[LAT][SD];
  __shared__ float b1s[HID];
  __shared__ float b2s[LAT][12];
  __shared__ float dbs[SD];

  const int tid = threadIdx.x;
  const int b0 = blockIdx.x * BT;

  // ---- weight staging ----
  for (int i=tid;i<HID*LAT;i+=THR){ int j = i & (HID-1); int k = i >> 7; W1t[j][k] = W1[k*HID+j]; }
  for (int i=tid;i<LAT*SD;i+=THR)  ((float*)dWs)[i] = decW[i];
  if (tid < HID) b1s[tid] = b1[tid];
  for (int i=tid;i<LAT*12;i+=THR){ int l=i/12, x=i%12; b2s[l][x] = (x<9)? b2[l*9+x] : 0.f; }
  if (tid < SD) dbs[tid] = decb[tid];

  // ---- ownership ----
  const int ol = tid >> 4;    // 0..63 latent l
  const int jg = tid & 15;    // 0..15 j-group / RK4 b-owner

  // ---- W2 -> registers as channel pairs ----
  f32x2 wpk[8][4]; f32x2 wc0pk[4];
  {
    #pragma unroll
    for (int jj=0;jj<8;jj++){
      const f32x2* p2 = (const f32x2*)&W2p8[((size_t)(jg*8+jj)*LAT + ol)*8];
      wpk[jj][0]=p2[0]; wpk[jj][1]=p2[1]; wpk[jj][2]=p2[2]; wpk[jj][3]=p2[3];
    }
    #pragma unroll
    for (int q=0;q<4;q++){
      wc0pk[q].x = W2c0[(jg*8+2*q)*LAT + ol];
      wc0pk[q].y = W2c0[(jg*8+2*q+1)*LAT + ol];
    }
  }
  const f32x2 one11 = {1.0f, 1.0f};

  // ---- encode z0 ----
  {
    const int bb = tid >> 6;
    const int li = tid & 63;
    const float* sb = s + (size_t)(b0+bb)*Lsz*SD;
    const float* ab = a + (size_t)(b0+bb)*Lsz*AD;
    const float tv = t[(size_t)(b0+bb)*Lsz];
    float acc = encb[li];
    #pragma unroll
    for (int k=0;k<SD;k++) acc = fmaf(sb[k], encW[k*LAT+li], acc);
    #pragma unroll
    for (int k=0;k<AD;k++) acc = fmaf(ab[k], encW[(SD+k)*LAT+li], acc);
    acc = fmaf(tv, encW[(SD+AD)*LAT+li], acc);
    zs[bb][li] = acc;
  }
  __syncthreads();

  // ---- decode out[:,0,:] ----
  if (tid < BT*SD){
    const int bb = tid >> 5; const int o = tid & 31;
    float acc = dbs[o];
    #pragma unroll 8
    for (int k=0;k<LAT;k++) acc = fmaf(zs[bb][k], dWs[k][o], acc);
    out[((size_t)(b0+bb)*Lsz + 0)*SD + o] = acc;
  }

  // RK4 state: thread owns z(l=ol, b=jg)
  float zb = zs[jg][ol];
  float ka = 0.f;

  const int hwaddr = (jg>>1)*HPROW + (ol>>2)*20 + ((2*ol)&7)*2 + (jg&1);

  for (int iv=0; iv<NI; iv++){
    // ---- dX(u) channels 1..8, pair layout ----
    if (tid < 5*BT*8){
      int ui = tid >> 7; int r = tid & 127; int bb = r >> 3; int x8 = r & 7;
      float u = 0.25f*(float)ui;
      int gb = b0+bb;
      float m0 = m_ws[((size_t)iv    *Bsz + gb)*8 + x8];
      float m1 = m_ws[((size_t)(iv+1)*Bsz + gb)*8 + x8];
      float xd = a[((size_t)gb*Lsz + iv+1)*AD + x8] - a[((size_t)gb*Lsz + iv)*AD + x8];
      float cb = xd - (2.f*m0 + m1)*(1.f/6.f);
      float cc = 0.5f*m0;
      float cd = (m1 - m0)*(1.f/6.f);
      dXp[ui*160 + (bb>>1)*DXROW + x8*2 + (bb&1)] = cb + (2.f*cc)*u + (3.f*cd)*(u*u);
    }

    for (int st=0; st<8; st++){
      const int ui = (st+1)>>1;      // {0,1,1,2,2,3,3,4}
      const int mode = st & 3;
      __syncthreads();               // zs, dXp readable; prev hp readers done

      // ---- GEMM1: h[jg][2ol..2ol+1] = relu(z @ W1 + b1) ----
      {
        const int j0 = 2*ol;
        float acc0 = b1s[j0], acc1 = b1s[j0+1];
        const float4* z4 = (const float4*)&zs[jg][0];
        const float4* w0 = (const float4*)&W1t[j0][0];
        const float4* w1 = (const float4*)&W1t[j0+1][0];
        #pragma unroll
        for (int k4=0;k4<LAT/4;k4++){
          float4 zv = z4[k4]; float4 u0 = w0[k4]; float4 u1 = w1[k4];
          acc0 = fmaf(zv.x,u0.x,acc0); acc0 = fmaf(zv.y,u0.y,acc0);
          acc0 = fmaf(zv.z,u0.z,acc0); acc0 = fmaf(zv.w,u0.w,acc0);
          acc1 = fmaf(zv.x,u1.x,acc1); acc1 = fmaf(zv.y,u1.y,acc1);
          acc1 = fmaf(zv.z,u1.z,acc1); acc1 = fmaf(zv.w,u1.w,acc1);
        }
        hp[hwaddr]   = fmaxf(acc0, 0.f);
        hp[hwaddr+2] = fmaxf(acc1, 0.f);
      }
      __syncthreads();               // hp ready

      // ---- GEMM2 packed over b-pairs: two batches of 4 pairs ----
      f32x2 tot0, tot1;
      #pragma unroll
      for (int bbat=0; bbat<2; bbat++){
        f32x2 dzp[4];
        #pragma unroll
        for (int i=0;i<4;i++){ dzp[i].x = 0.f; dzp[i].y = 0.f; }
        #pragma unroll
        for (int pi=0; pi<4; pi++){
          const int p = bbat*4 + pi;
          const f32x4* dxq = (const f32x4*)&dXp[ui*160 + p*DXROW];
          const f32x4* hq  = (const f32x4*)&hp[p*HPROW + jg*20];
          f32x4 d0=dxq[0], d1=dxq[1], d2=dxq[2], d3=dxq[3];
          f32x4 g0=hq[0],  g1=hq[1],  g2=hq[2],  g3=hq[3];
          f32x2 dx2[8] = {LO2(d0),HI2(d0),LO2(d1),HI2(d1),LO2(d2),HI2(d2),LO2(d3),HI2(d3)};
          f32x2 hh [8] = {LO2(g0),HI2(g0),LO2(g1),HI2(g1),LO2(g2),HI2(g2),LO2(g3),HI2(g3)};
          #pragma unroll
          for (int jj=0;jj<8;jj++){
            f32x2 wd;
            PK_MUL_BCLO(wd, wpk[jj][0], dx2[0]);
            PK_FMA_BCHI(wd, wpk[jj][0], dx2[1]);
            PK_FMA_BCLO(wd, wpk[jj][1], dx2[2]);
            PK_FMA_BCHI(wd, wpk[jj][1], dx2[3]);
            PK_FMA_BCLO(wd, wpk[jj][2], dx2[4]);
            PK_FMA_BCHI(wd, wpk[jj][2], dx2[5]);
            PK_FMA_BCLO(wd, wpk[jj][3], dx2[6]);
            PK_FMA_BCHI(wd, wpk[jj][3], dx2[7]);
            if ((jj&1)==0){ PK_FMA_BCLO(wd, wc0pk[jj>>1], one11); }
            else          { PK_FMA_BCHI(wd, wc0pk[jj>>1], one11); }
            PK_FMA(dzp[pi], hh[jj], wd);
          }
        }
        // ---- packed butterfly: b-bit1 (lane^2), b-bit2 (lane^4), then full add over lane^8 ----
        const bool g1 = (jg>>1)&1;
        f32x2 nd[2];
        #pragma unroll
        for (int i=0;i<2;i++){
          f32x2 lo = dzp[2*i], hi = dzp[2*i+1];
          f32x2 send = g1 ? lo : hi;
          f32x2 recv; recv.x = DPP_XOR2(send.x); recv.y = DPP_XOR2(send.y);
          f32x2 keep = g1 ? hi : lo;
          PK_ADD(nd[i], keep, recv);
        }
        const bool g2 = (jg>>2)&1;
        f32x2 md;
        {
          f32x2 lo = nd[0], hi = nd[1];
          f32x2 send = g2 ? lo : hi;
          f32x2 recv; recv.x = SWZ_XOR4(send.x); recv.y = SWZ_XOR4(send.y);
          f32x2 keep = g2 ? hi : lo;
          PK_ADD(md, keep, recv);
        }
        f32x2 r8; r8.x = SWZ_XOR8(md.x); r8.y = SWZ_XOR8(md.y);
        f32x2 totv; PK_ADD(totv, md, r8);
        if (bbat==0) tot0 = totv; else tot1 = totv;
      }
      // ---- batch select (b-bit3) + b-bit0 via component exchange (lane^1) ----
      f32x2 sel = (jg&8) ? tot1 : tot0;
      float own = (jg&1) ? sel.y : sel.x;
      float oth = (jg&1) ? sel.x : sel.y;
      float dzm = own + DPP_XOR1(oth);

      // ---- bias: b2[ol]·dX[b=jg] (+ const t-channel) ----
      {
        const f32x4* dxb = (const f32x4*)&dXp[ui*160 + (jg>>1)*DXROW];
        f32x4 q0=dxb[0], q1=dxb[1], q2=dxb[2], q3=dxb[3];
        const bool hi = (jg&1);
        float d0 = hi? q0.y:q0.x, d1 = hi? q0.w:q0.z;
        float d2 = hi? q1.y:q1.x, d3 = hi? q1.w:q1.z;
        float d4 = hi? q2.y:q2.x, d5 = hi? q2.w:q2.z;
        float d6 = hi? q3.y:q3.x, d7 = hi? q3.w:q3.z;
        const float4 ba = *(const float4*)&b2s[ol][0];
        const float4 bb4 = *(const float4*)&b2s[ol][4];
        float bias = fmaf(ba.y,d0, fmaf(ba.z,d1, fmaf(ba.w,d2, fmaf(bb4.x,d3,
                     fmaf(bb4.y,d4, fmaf(bb4.z,d5, fmaf(bb4.w,d6, fmaf(b2s[ol][8],d7, ba.x))))))));
        dzm += bias;
      }

      // ---- RK4 bookkeeping (h = 0.5) ----
      if (mode == 0){        ka = dzm;
        zs[jg][ol] = zb + 0.25f*dzm;
      } else if (mode == 1){ ka = fmaf(2.f, dzm, ka);
        zs[jg][ol] = zb + 0.25f*dzm;
      } else if (mode == 2){ ka = fmaf(2.f, dzm, ka);
        zs[jg][ol] = zb + 0.5f*dzm;
      } else {               ka += dzm;
        zb = fmaf(0.5f/6.f, ka, zb);
        zs[jg][ol] = zb;
      }
    }

    __syncthreads();   // final z in zs
    // ---- decode out[:, iv+1, :] ----
    if (tid < BT*SD){
      const int bb = tid >> 5; const int o = tid & 31;
      float acc = dbs[o];
      #pragma unroll 8
      for (int k=0;k<LAT;k++) acc = fmaf(zs[bb][k], dWs[k][o], acc);
      out[((size_t)(b0+bb)*Lsz + (iv+1))*SD + o] = acc;
    }
  }
}

extern "C" void kernel_launch(void* const* d_in, const int* in_sizes, int n_in,
                              void* d_out, int out_size, void* d_ws, size_t ws_size,
                              hipStream_t stream){
  const float* s    = (const float*)d_in[0];
  const float* a    = (const float*)d_in[1];
  const float* t    = (const float*)d_in[2];
  const float* encW = (const float*)d_in[3];
  const float* encb = (const float*)d_in[4];
  const float* W1   = (const float*)d_in[5];
  const float* b1   = (const float*)d_in[6];
  const float* W2   = (const float*)d_in[7];
  const float* b2   = (const float*)d_in[8];
  const float* decW = (const float*)d_in[9];
  const float* decb = (const float*)d_in[10];
  float* out = (float*)d_out;
  float* ws  = (float*)d_ws;
  float* W2p8 = ws;                          // 65,536 floats
  float* W2c0 = ws + HID*LAT*8;              //  8,192 floats
  float* m_ws = ws + HID*LAT*9;              // 128*4096*8 floats (16.8MB)

  hipLaunchKernelGGL(repack_w2, dim3((HID*LAT*9+255)/256), dim3(256), 0, stream, W2, W2p8, W2c0);
  hipLaunchKernelGGL(spline_kernel, dim3(Bsz*8/256), dim3(256), 0, stream, a, m_ws);
  hipLaunchKernelGGL(cde_integrate, dim3(Bsz/BT), dim3(THR), 0, stream,
                     s,a,t,encW,encb,W1,b1,b2,decW,decb,W2p8,W2c0,m_ws,out);
}

// Round 8
// 8485.958 us; speedup vs baseline: 1.0419x; 1.0419x over previous
//
#include <hip/hip_runtime.h>

#define Bsz 4096
#define Lsz 128
#define NI  127
#define SD  32
#define AD  8
#define LAT 64
#define HID 128
#define BT  16
#define THR 512

typedef float f32x2 __attribute__((ext_vector_type(2)));
typedef float f32x4 __attribute__((ext_vector_type(4)));

// ---------------- W2 repack ----------------
// W2 [128][64][9] -> W2p8 [j][l][8] (channels 1..8) + W2c0 [j][l] (channel 0)
__global__ __launch_bounds__(256) void repack_w2(const float* __restrict__ W2,
                                                 float* __restrict__ W2p8,
                                                 float* __restrict__ W2c0){
  int idx = blockIdx.x*256 + threadIdx.x;
  if (idx < HID*LAT*8){
    int x = idx & 7; int jl = idx >> 3; int l = jl & 63; int j = jl >> 6;
    W2p8[idx] = W2[(j*LAT + l)*9 + x + 1];
  } else if (idx < HID*LAT*9){
    int jl = idx - HID*LAT*8;
    W2c0[jl] = W2[(size_t)jl*9];
  }
}

// ---------------- Natural cubic spline: channels 1..8 (t-channel exactly linear) ----------------
__global__ __launch_bounds__(256) void spline_kernel(const float* __restrict__ a,
                                                     float* __restrict__ m_ws){
  __shared__ float cp_s[126];
  if (threadIdx.x == 0){
    float c = 0.25f; cp_s[0] = c;
    for (int i=1;i<126;i++){ c = 1.0f/(4.0f - c); cp_s[i] = c; }
  }
  __syncthreads();
  int tid = blockIdx.x*256 + threadIdx.x;   // tid = b*8 + c8
  int b = tid >> 3, c8 = tid & 7;
  float dp[126];
  const float* ab = a + (size_t)b*Lsz*AD + c8;
  float x0 = ab[0];
  float x1 = ab[AD];
  for (int i=0;i<126;i++){
    float x2 = ab[(size_t)(i+2)*AD];
    float rhs = 6.0f*(x2 - 2.0f*x1 + x0);
    dp[i] = (i==0)? rhs*0.25f : (rhs - dp[i-1])*cp_s[i];
    x0 = x1; x1 = x2;
  }
  m_ws[tid] = 0.0f;
  m_ws[((size_t)127*Bsz)*8 + tid] = 0.0f;
  float mn = 0.0f;
  for (int k=125;k>=0;k--){
    mn = dp[k] - cp_s[k]*mn;
    m_ws[((size_t)(k+1)*Bsz)*8 + tid] = mn;
  }
}

// ---- cross-lane helpers (32-bit) ----
#define DPP_XOR1(v) __int_as_float(__builtin_amdgcn_mov_dpp(__float_as_int(v), 0xB1, 0xF, 0xF, true))
#define DPP_XOR2(v) __int_as_float(__builtin_amdgcn_mov_dpp(__float_as_int(v), 0x4E, 0xF, 0xF, true))
#define SWZ_XOR4(v) __int_as_float(__builtin_amdgcn_ds_swizzle(__float_as_int(v), 0x101F))

// ---- packed fp32 ops (VOP3P). BCLO/BCHI broadcast src0's lo/hi half to both result halves ----
#define PK_MUL_BCLO(d, w, x) asm("v_pk_mul_f32 %0, %1, %2 op_sel:[0,0] op_sel_hi:[0,1]" : "=v"(d) : "v"(w), "v"(x))
#define PK_MUL_BCHI(d, w, x) asm("v_pk_mul_f32 %0, %1, %2 op_sel:[1,0] op_sel_hi:[1,1]" : "=v"(d) : "v"(w), "v"(x))
#define PK_FMA_BCLO(acc, w, x) asm("v_pk_fma_f32 %0, %1, %2, %0 op_sel:[0,0,0] op_sel_hi:[0,1,1]" : "+v"(acc) : "v"(w), "v"(x))
#define PK_FMA_BCHI(acc, w, x) asm("v_pk_fma_f32 %0, %1, %2, %0 op_sel:[1,0,0] op_sel_hi:[1,1,1]" : "+v"(acc) : "v"(w), "v"(x))
#define PK_FMA(acc, a, b)      asm("v_pk_fma_f32 %0, %1, %2, %0" : "+v"(acc) : "v"(a), "v"(b))
#define PK_ADD(d, a, b)        asm("v_pk_add_f32 %0, %1, %2" : "=v"(d) : "v"(a), "v"(b))

#define LO2(v4) __builtin_shufflevector(v4, v4, 0, 1)
#define HI2(v4) __builtin_shufflevector(v4, v4, 2, 3)

// ---------------- Persistent RK4 integrator: 512 thr, 256-reg budget, all-packed ----------------
__attribute__((amdgpu_waves_per_eu(2,2)))
__global__ __launch_bounds__(THR) void cde_integrate(
    const float* __restrict__ s, const float* __restrict__ a, const float* __restrict__ t,
    const float* __restrict__ encW, const float* __restrict__ encb,
    const float* __restrict__ W1, const float* __restrict__ b1,
    const float* __restrict__ b2, const float* __restrict__ decW, const float* __restrict__ decb,
    const float* __restrict__ W2p8, const float* __restrict__ W2c0, const float* __restrict__ m_ws,
    float* __restrict__ out)
{
  __shared__ float W1t[HID][LAT+4];   // [j][k], row 68 (272B, 16B-aligned)
  __shared__ float hp[8][292];        // [b-pair][jblock*36 + chunk*4 + {e0,o0,e1,o1}]
  __shared__ float zp[8][132];        // [b-pair][l*2 + c]
  __shared__ float dXp[5][8][20];     // [u][b-pair][x8*2 + c]
  __shared__ float dWs[LAT][SD];
  __shared__ float dbs[SD];

  const int tid = threadIdx.x;
  const int b0 = blockIdx.x * BT;
  const int ol = tid >> 3;   // 0..63 : latent l (GEMM2/RK4), j-pair (GEMM1)
  const int jg = tid & 7;    // 0..7  : j-group (GEMM2), b-pair (GEMM1/RK4)

  // ---- LDS weight staging ----
  for (int i=tid;i<HID*LAT;i+=THR){ int j = i & (HID-1); int k = i >> 7; W1t[j][k] = W1[k*HID+j]; }
  for (int i=tid;i<LAT*SD;i+=THR)  ((float*)dWs)[i] = decW[i];
  if (tid < SD) dbs[tid] = decb[tid];

  // ---- W2 -> arch VGPRs as b?no: channel pairs; j set = jg*16..+15 at column ol ----
  f32x2 wpk[16][4]; f32x2 wc0pk[8];
  {
    #pragma unroll
    for (int jj=0;jj<16;jj++){
      const f32x2* p2 = (const f32x2*)&W2p8[((size_t)(jg*16+jj)*LAT + ol)*8];
      wpk[jj][0]=p2[0]; wpk[jj][1]=p2[1]; wpk[jj][2]=p2[2]; wpk[jj][3]=p2[3];
    }
    #pragma unroll
    for (int q=0;q<8;q++){
      wc0pk[q].x = W2c0[(jg*16+2*q)*LAT + ol];
      wc0pk[q].y = W2c0[(jg*16+2*q+1)*LAT + ol];
    }
    #pragma unroll
    for (int jj=0;jj<16;jj++){
      asm volatile("" : "+v"(wpk[jj][0]), "+v"(wpk[jj][1]), "+v"(wpk[jj][2]), "+v"(wpk[jj][3]));
    }
  }
  f32x2 b2p[4]; f32x2 b2c0v; f32x2 b1pair; f32x2 one11; one11.x = 1.f; one11.y = 1.f;
  {
    const float* bp = b2 + ol*9;
    b2c0v.x = bp[0]; b2c0v.y = 0.f;
    b2p[0].x = bp[1]; b2p[0].y = bp[2];
    b2p[1].x = bp[3]; b2p[1].y = bp[4];
    b2p[2].x = bp[5]; b2p[2].y = bp[6];
    b2p[3].x = bp[7]; b2p[3].y = bp[8];
    b1pair.x = b1[2*ol]; b1pair.y = b1[2*ol+1];
  }

  // ---- encode z0: thread handles (b, b+8) for b = tid>>6, l = tid&63 ----
  {
    const int bb8 = tid >> 6;        // 0..7
    const int li = tid & 63;
    #pragma unroll
    for (int h=0; h<2; h++){
      const int b = bb8 + 8*h;
      const float* sb = s + (size_t)(b0+b)*Lsz*SD;
      const float* ab = a + (size_t)(b0+b)*Lsz*AD;
      const float tv = t[(size_t)(b0+b)*Lsz];
      float acc = encb[li];
      #pragma unroll
      for (int k=0;k<SD;k++) acc = fmaf(sb[k], encW[k*LAT+li], acc);
      #pragma unroll
      for (int k=0;k<AD;k++) acc = fmaf(ab[k], encW[(SD+k)*LAT+li], acc);
      acc = fmaf(tv, encW[(SD+AD)*LAT+li], acc);
      zp[b>>1][li*2 + (b&1)] = acc;
    }
  }
  __syncthreads();

  // ---- decode out[:,0,:] ----
  {
    const int bb = tid >> 5; const int o = tid & 31; const int c = bb & 1;
    const float* zrow = &zp[bb>>1][0];
    float acc = dbs[o];
    #pragma unroll 16
    for (int k=0;k<LAT;k++) acc = fmaf(zrow[2*k+c], dWs[k][o], acc);
    out[((size_t)(b0+bb)*Lsz + 0)*SD + o] = acc;
  }

  // ---- RK4 packed state: thread owns l=ol, b-pair jg (b = 2jg, 2jg+1) ----
  float zb0, zb1, ka0 = 0.f, ka1 = 0.f;
  { f32x2 zr = *(const f32x2*)&zp[jg][2*ol]; zb0 = zr.x; zb1 = zr.y; }

  #pragma unroll 1
  for (int iv=0; iv<NI; iv++){
    // ---- dX(u) channels 1..8, pair layout; 640 entries ----
    for (int idx=tid; idx<5*BT*8; idx+=THR){
      int ui = idx >> 7; int r = idx & 127; int bb = r >> 3; int x8 = r & 7;
      float u = 0.25f*(float)ui;
      int gb = b0+bb;
      float m0 = m_ws[((size_t)iv    *Bsz + gb)*8 + x8];
      float m1 = m_ws[((size_t)(iv+1)*Bsz + gb)*8 + x8];
      float xd = a[((size_t)gb*Lsz + iv+1)*AD + x8] - a[((size_t)gb*Lsz + iv)*AD + x8];
      float cb = xd - (2.f*m0 + m1)*(1.f/6.f);
      float cc = 0.5f*m0;
      float cd = (m1 - m0)*(1.f/6.f);
      dXp[ui][bb>>1][x8*2 + (bb&1)] = cb + (2.f*cc)*u + (3.f*cd)*(u*u);
    }

    #pragma unroll 1
    for (int st=0; st<8; st++){
      const int ui = (st+1)>>1;      // {0,1,1,2,2,3,3,4}
      const int mode = st & 3;
      __syncthreads();               // zp, dXp ready; prev hp readers done

      // ---- GEMM1 packed: h[b-pair jg][j=2ol,2ol+1] ----
      {
        const int j0 = 2*ol;
        f32x2 acc0, acc1;
        PK_MUL_BCLO(acc0, b1pair, one11);   // {b1[j0], b1[j0]}
        PK_MUL_BCHI(acc1, b1pair, one11);   // {b1[j0+1], b1[j0+1]}
        const f32x4* zrow = (const f32x4*)&zp[jg][0];
        const f32x4* w0r = (const f32x4*)&W1t[j0][0];
        const f32x4* w1r = (const f32x4*)&W1t[j0+1][0];
        #pragma unroll
        for (int k16=0;k16<16;k16++){
          f32x4 zqA = zrow[2*k16], zqB = zrow[2*k16+1];
          f32x4 w0q = w0r[k16], w1q = w1r[k16];
          f32x2 w0l = LO2(w0q), w0h = HI2(w0q), w1l = LO2(w1q), w1h = HI2(w1q);
          f32x2 zA0 = LO2(zqA), zA1 = HI2(zqA), zB0 = LO2(zqB), zB1 = HI2(zqB);
          PK_FMA_BCLO(acc0, w0l, zA0); PK_FMA_BCHI(acc0, w0l, zA1);
          PK_FMA_BCLO(acc0, w0h, zB0); PK_FMA_BCHI(acc0, w0h, zB1);
          PK_FMA_BCLO(acc1, w1l, zA0); PK_FMA_BCHI(acc1, w1l, zA1);
          PK_FMA_BCLO(acc1, w1h, zB0); PK_FMA_BCHI(acc1, w1h, zB1);
        }
        f32x4 hv;
        hv.x = fmaxf(acc0.x, 0.f); hv.y = fmaxf(acc0.y, 0.f);
        hv.z = fmaxf(acc1.x, 0.f); hv.w = fmaxf(acc1.y, 0.f);
        *(f32x4*)&hp[jg][(ol>>3)*36 + (ol&7)*4] = hv;
      }
      __syncthreads();               // hp ready

      // ---- GEMM2 packed over b-pairs ----
      f32x2 dz[8];
      #pragma unroll
      for (int p=0;p<8;p++){
        const f32x4* dxr = (const f32x4*)&dXp[ui][p][0];
        f32x4 d0=dxr[0], d1=dxr[1], d2=dxr[2], d3=dxr[3];
        f32x2 dx2[8] = {LO2(d0),HI2(d0),LO2(d1),HI2(d1),LO2(d2),HI2(d2),LO2(d3),HI2(d3)};
        const f32x4* hr = (const f32x4*)&hp[p][jg*36];
        f32x2 acc; acc.x = 0.f; acc.y = 0.f;
        #pragma unroll
        for (int jj2=0;jj2<8;jj2++){
          f32x4 hq = hr[jj2];
          f32x2 hl = LO2(hq), hh = HI2(hq);
          {
            f32x2 wd;
            PK_MUL_BCLO(wd, wpk[2*jj2][0], dx2[0]); PK_FMA_BCHI(wd, wpk[2*jj2][0], dx2[1]);
            PK_FMA_BCLO(wd, wpk[2*jj2][1], dx2[2]); PK_FMA_BCHI(wd, wpk[2*jj2][1], dx2[3]);
            PK_FMA_BCLO(wd, wpk[2*jj2][2], dx2[4]); PK_FMA_BCHI(wd, wpk[2*jj2][2], dx2[5]);
            PK_FMA_BCLO(wd, wpk[2*jj2][3], dx2[6]); PK_FMA_BCHI(wd, wpk[2*jj2][3], dx2[7]);
            PK_FMA_BCLO(wd, wc0pk[jj2], one11);
            PK_FMA(acc, hl, wd);
          }
          {
            f32x2 wd;
            PK_MUL_BCLO(wd, wpk[2*jj2+1][0], dx2[0]); PK_FMA_BCHI(wd, wpk[2*jj2+1][0], dx2[1]);
            PK_FMA_BCLO(wd, wpk[2*jj2+1][1], dx2[2]); PK_FMA_BCHI(wd, wpk[2*jj2+1][1], dx2[3]);
            PK_FMA_BCLO(wd, wpk[2*jj2+1][2], dx2[4]); PK_FMA_BCHI(wd, wpk[2*jj2+1][2], dx2[5]);
            PK_FMA_BCLO(wd, wpk[2*jj2+1][3], dx2[6]); PK_FMA_BCHI(wd, wpk[2*jj2+1][3], dx2[7]);
            PK_FMA_BCHI(wd, wc0pk[jj2], one11);
            PK_FMA(acc, hh, wd);
          }
        }
        dz[p] = acc;
      }

      // ---- butterfly over 8 jg lanes: 3 rounds -> lane jg owns pair jg ----
      const bool g1 = jg & 1;
      f32x2 n4[4];
      #pragma unroll
      for (int i=0;i<4;i++){
        f32x2 lo = dz[2*i], hi = dz[2*i+1];
        f32x2 send = g1 ? lo : hi;
        f32x2 recv; recv.x = DPP_XOR1(send.x); recv.y = DPP_XOR1(send.y);
        f32x2 keep = g1 ? hi : lo;
        PK_ADD(n4[i], keep, recv);
      }
      const bool g2 = jg & 2;
      f32x2 n2[2];
      #pragma unroll
      for (int i=0;i<2;i++){
        f32x2 lo = n4[2*i], hi = n4[2*i+1];
        f32x2 send = g2 ? lo : hi;
        f32x2 recv; recv.x = DPP_XOR2(send.x); recv.y = DPP_XOR2(send.y);
        f32x2 keep = g2 ? hi : lo;
        PK_ADD(n2[i], keep, recv);
      }
      const bool g4 = jg & 4;
      f32x2 res;
      {
        f32x2 lo = n2[0], hi = n2[1];
        f32x2 send = g4 ? lo : hi;
        f32x2 recv; recv.x = SWZ_XOR4(send.x); recv.y = SWZ_XOR4(send.y);
        f32x2 keep = g4 ? hi : lo;
        PK_ADD(res, keep, recv);
      }

      // ---- bias: b2[ol]·dX[b-pair jg] (+ const t-channel), packed ----
      f32x2 bias2;
      {
        const f32x4* dxb = (const f32x4*)&dXp[ui][jg][0];
        f32x4 e0=dxb[0], e1=dxb[1], e2=dxb[2], e3=dxb[3];
        PK_MUL_BCLO(bias2, b2c0v, one11);           // {c0, c0}
        PK_FMA_BCLO(bias2, b2p[0], LO2(e0)); PK_FMA_BCHI(bias2, b2p[0], HI2(e0));
        PK_FMA_BCLO(bias2, b2p[1], LO2(e1)); PK_FMA_BCHI(bias2, b2p[1], HI2(e1));
        PK_FMA_BCLO(bias2, b2p[2], LO2(e2)); PK_FMA_BCHI(bias2, b2p[2], HI2(e2));
        PK_FMA_BCLO(bias2, b2p[3], LO2(e3)); PK_FMA_BCHI(bias2, b2p[3], HI2(e3));
      }
      f32x2 dzm2; PK_ADD(dzm2, res, bias2);
      const float dz0 = dzm2.x, dz1 = dzm2.y;

      // ---- RK4 bookkeeping (h = 0.5), two scalar states ----
      float zn0, zn1;
      if (mode == 0){
        ka0 = dz0; ka1 = dz1;
        zn0 = fmaf(0.25f, dz0, zb0); zn1 = fmaf(0.25f, dz1, zb1);
      } else if (mode == 1){
        ka0 = fmaf(2.f, dz0, ka0); ka1 = fmaf(2.f, dz1, ka1);
        zn0 = fmaf(0.25f, dz0, zb0); zn1 = fmaf(0.25f, dz1, zb1);
      } else if (mode == 2){
        ka0 = fmaf(2.f, dz0, ka0); ka1 = fmaf(2.f, dz1, ka1);
        zn0 = fmaf(0.5f, dz0, zb0); zn1 = fmaf(0.5f, dz1, zb1);
      } else {
        ka0 += dz0; ka1 += dz1;
        zb0 = fmaf(0.5f/6.f, ka0, zb0); zb1 = fmaf(0.5f/6.f, ka1, zb1);
        zn0 = zb0; zn1 = zb1;
      }
      f32x2 zw; zw.x = zn0; zw.y = zn1;
      *(f32x2*)&zp[jg][2*ol] = zw;
    }

    __syncthreads();   // final z in zp; also fences dXp reads before next staging
    // ---- decode out[:, iv+1, :] ----
    {
      const int bb = tid >> 5; const int o = tid & 31; const int c = bb & 1;
      const float* zrow = &zp[bb>>1][0];
      float acc = dbs[o];
      #pragma unroll 16
      for (int k=0;k<LAT;k++) acc = fmaf(zrow[2*k+c], dWs[k][o], acc);
      out[((size_t)(b0+bb)*Lsz + (iv+1))*SD + o] = acc;
    }
  }
}

extern "C" void kernel_launch(void* const* d_in, const int* in_sizes, int n_in,
                              void* d_out, int out_size, void* d_ws, size_t ws_size,
                              hipStream_t stream){
  const float* s    = (const float*)d_in[0];
  const float* a    = (const float*)d_in[1];
  const float* t    = (const float*)d_in[2];
  const float* encW = (const float*)d_in[3];
  const float* encb = (const float*)d_in[4];
  const float* W1   = (const float*)d_in[5];
  const float* b1   = (const float*)d_in[6];
  const float* W2   = (const float*)d_in[7];
  const float* b2   = (const float*)d_in[8];
  const float* decW = (const float*)d_in[9];
  const float* decb = (const float*)d_in[10];
  float* out = (float*)d_out;
  float* ws  = (float*)d_ws;
  float* W2p8 = ws;                          // 65,536 floats
  float* W2c0 = ws + HID*LAT*8;              //  8,192 floats
  float* m_ws = ws + HID*LAT*9;              // 128*4096*8 floats (16.8MB)

  hipLaunchKernelGGL(repack_w2, dim3((HID*LAT*9+255)/256), dim3(256), 0, stream, W2, W2p8, W2c0);
  hipLaunchKernelGGL(spline_kernel, dim3(Bsz*8/256), dim3(256), 0, stream, a, m_ws);
  hipLaunchKernelGGL(cde_integrate, dim3(Bsz/BT), dim3(THR), 0, stream,
                     s,a,t,encW,encb,W1,b1,b2,decW,decb,W2p8,W2c0,m_ws,out);
}